// Round 5
// baseline (195.527 us; speedup 1.0000x reference)
//
#include <hip/hip_runtime.h>
#include <math.h>

#define DIM 192
#define OD  191          // output domain per axis
#define PLANE 36864      // 192*192
#define VOL 7077888      // 192^3
#define TW  14           // tile width  (w)  -> 16-lane DPP row covers 16-wide halo
#define TH  16           // tile height (h)
#define CD  16           // d-planes per chunk
#define NBW 14           // ceil(191/14)
#define NBH 12           // ceil(191/16)
#define NCH 12           // 12*16 = 192 >= 191

typedef float    f4 __attribute__((ext_vector_type(4)));
typedef _Float16 h8 __attribute__((ext_vector_type(8)));
typedef _Float16 h4 __attribute__((ext_vector_type(4)));
typedef _Float16 h2 __attribute__((ext_vector_type(2)));

template<int CTRL>
__device__ __forceinline__ int dppi(int x) {
    // bound_ctrl=true: out-of-row / exec-off source reads as 0 (matches zero padding)
    return __builtin_amdgcn_update_dpp(0, x, CTRL, 0xF, 0xF, true);
}

union U8 { h8 v; int i[4]; };
union U2 { h2 v; int i; };

// Symmetric 3-tap w-window sum across a 16-lane DPP row:
//   out(lane) = in(lane-1) + in(lane) + in(lane+1), 0 outside the row.
__device__ __forceinline__ void wsum3(h8& a, h2& b) {
    U8 ua, s1, s2;
    ua.v = a;
    #pragma unroll
    for (int k = 0; k < 4; ++k) {
        s1.i[k] = dppi<0x101>(ua.i[k]);   // row_shl:1
        s2.i[k] = dppi<0x111>(ua.i[k]);   // row_shr:1
    }
    a = ua.v + s1.v + s2.v;
    U2 ub, t1, t2;
    ub.v = b;
    t1.i = dppi<0x101>(ub.i);
    t2.i = dppi<0x111>(ub.i);
    b = ub.v + t1.v + t2.v;
}

// Packed-f16 diff: c=center, cw=w+1, ch=h+1, cd=d+1 (all h4 {x,y,z,0}).
// Field order: va={hx,hy,hz,dx,dy,dz,wx,wy}, vb={wz,0}.
__device__ __forceinline__ void make_diff16(const h4 c, const h4 cw, const h4 ch, const h4 cd,
                                            h8& va, h2& vb) {
    const h4 dh = __builtin_elementwise_abs(ch - c);
    const h4 dd = __builtin_elementwise_abs(cd - c);
    const h4 dw = __builtin_elementwise_abs(cw - c);
    va = (h8){dh[0], dh[1], dh[2], dd[0], dd[1], dd[2], dw[0], dw[1]};
    vb = (h2){dw[2], (_Float16)0.f};
}

// Raw f32 load, NO dependent arithmetic -> vmcnt wait can drift into later
// iterations (this is what keeps the software pipeline asynchronous).
__device__ __forceinline__ f4 ld3(const float* __restrict__ P, int idx, bool ok) {
    f4 r = (f4)0;
    if (ok) {
        r.x = P[idx];
        r.y = P[idx + VOL];
        r.z = P[idx + 2 * VOL];
    }
    return r;
}

// f32 -> packed f16, done at STORE time (one plane after the load issued).
__device__ __forceinline__ h4 cvt16(const f4 v) {
    return (h4){(_Float16)v.x, (_Float16)v.y, (_Float16)v.z, (_Float16)0.f};
}

// Fused: diff -> separable 3x3x3 box mean (w: DPP, h: LDS 3-tap, z: register
// ring) -> neo-hookean energy -> mean reduction.
// Round-5: raw-f32 2-deep prefetch (loads have no same-iteration consumers;
// f32->f16 cvt deferred to store time) + f16-packed LDS/diff math.
__global__ __launch_bounds__(256, 8)
void nh_fused_kernel(const float* __restrict__ P, float* __restrict__ out) {
    const int tid = threadIdx.x;
    const int tx  = tid & 15;        // lane within DPP row == w within halo
    const int ty  = tid >> 4;        // h within tile
    const int w0  = blockIdx.x * TW;
    const int h0  = blockIdx.y * TH;
    const int ds  = blockIdx.z * CD;
    const int de  = min(ds + CD, OD);

    __shared__ h4 sraw[2][19][18];   // raw y_pred (f16 packed), rows h0-1..h0+17, cols w0-1..w0+15
    __shared__ h8 sW[2][18][16];     // w-summed diffs, double-buffered by t parity
    __shared__ h2 sWB[2][18][16];    // w-summed {Wd2, 0}
    __shared__ float wsum[4];

    // ---- loop-invariant geometry ----
    // primary halo point (ty, tx): staged + built by every thread
    const int hp_p = h0 - 1 + ty;
    const int wp_p = w0 - 1 + tx;
    const bool in_raw_p  = (hp_p >= 0) & (hp_p < DIM) & (wp_p >= 0) & (wp_p < DIM);
    const bool in_diff_p = (hp_p >= 0) & (hp_p < OD)  & (wp_p >= 0) & (wp_p < OD);
    const int base_p = hp_p * DIM + wp_p;

    // leftover halo point: tids 0..47 -> rows 16..18 x cols 0..15 (so pass-2
    // threads 0..31 own exactly the rows-16/17 points they build);
    // tids 48..66 -> col 16, rows 0..18.
    int hh_l, ww_l;
    if (tid < 48) { hh_l = 16 + (tid >> 4); ww_l = tid & 15; }
    else          { hh_l = tid - 48;        ww_l = 16; }
    const bool has_l = (tid < 67);
    const int hp_l = h0 - 1 + hh_l;
    const int wp_l = w0 - 1 + ww_l;
    const bool in_raw_l  = has_l & (hp_l >= 0) & (hp_l < DIM) & (wp_l >= 0) & (wp_l < DIM);
    const bool in_diff_l = (tid < 32) & (hp_l >= 0) & (hp_l < OD) & (wp_l >= 0) & (wp_l < OD);
    const int base_l = hp_l * DIM + wp_l;

    const bool valid = (tx < TW) && (w0 + tx < OD) && (h0 + ty < OD);

    h8 a0 = (h8)0, a1 = (h8)0, a2 = (h8)0;
    h2 b0 = (h2)0, b1 = (h2)0, b2 = (h2)0;
    f4 cur_p = (f4)0, nxt_p = (f4)0;     // raw f32 ring: plane t, t+1
    f4 cur_l = (f4)0, nxt_l = (f4)0;
    h4 prev16_p = (h4)0, prev16_l = (h4)0;  // f16 of plane t-1 (for diff center)
    float acc = 0.f;

    // preload planes ds-1 (may be absent -> zeros) and ds (always exists)
    {
        const int t0 = ds - 1;
        if (t0 >= 0) {
            cur_p = ld3(P, t0 * PLANE + base_p, in_raw_p);
            cur_l = ld3(P, t0 * PLANE + base_l, in_raw_l);
        }
        nxt_p = ld3(P, ds * PLANE + base_p, in_raw_p);
        nxt_l = ld3(P, ds * PLANE + base_l, in_raw_l);
    }

    for (int t = ds - 1; t <= de + 1; ++t) {
        const int cb = t & 1, pb = cb ^ 1;

        // (1) prefetch plane t+2 into regs (consumed TWO iterations later ->
        //     ~2x per-plane compute window covers the ~900cy HBM latency)
        f4 n2_p = (f4)0, n2_l = (f4)0;
        {
            const int tn = t + 2;
            if ((tn < DIM) & (tn <= de + 1)) {       // wave-uniform
                n2_p = ld3(P, tn * PLANE + base_p, in_raw_p);
                n2_l = ld3(P, tn * PLANE + base_l, in_raw_l);
            }
        }

        // (2) convert plane t (loaded >=1 iteration ago) to f16, stage to LDS
        const h4 cur16_p = cvt16(cur_p);
        sraw[cb][ty][tx] = cur16_p;
        h4 cur16_l = (h4)0;
        if (has_l) {
            cur16_l = cvt16(cur_l);
            sraw[cb][hh_l][ww_l] = cur16_l;
        }

        // (3) build w-summed diff plane p = t-1 into sW[cb]
        //     reads ONLY sraw[pb] (synced last iteration) + registers
        const bool built = (t >= ds) & (t - 1 >= 0) & (t - 1 < OD);   // wave-uniform

        {   // pass 1: rows 0..15 (all threads)
            h8 sa = (h8)0; h2 sb = (h2)0;
            if (built) {
                h8 va = (h8)0; h2 vb = (h2)0;
                if (in_diff_p) {
                    make_diff16(prev16_p,
                                sraw[pb][ty][tx + 1],     // (p, hp, wp+1)
                                sraw[pb][ty + 1][tx],     // (p, hp+1, wp)
                                cur16_p, va, vb);
                }
                wsum3(va, vb);                            // all lanes participate
                sa = va; sb = vb;
            }
            sW[cb][ty][tx] = sa; sWB[cb][ty][tx] = sb;
        }
        if (tid < 32) {  // pass 2: rows 16,17 in ONE wave issue (two DPP rows)
            h8 sa = (h8)0; h2 sb = (h2)0;
            if (built) {
                h8 va = (h8)0; h2 vb = (h2)0;
                if (in_diff_l) {
                    make_diff16(prev16_l,
                                sraw[pb][hh_l][ww_l + 1],
                                sraw[pb][hh_l + 1][ww_l],
                                cur16_l, va, vb);
                }
                wsum3(va, vb);
                sa = va; sb = vb;
            }
            sW[cb][hh_l][ww_l] = sa; sWB[cb][hh_l][ww_l] = sb;
        }

        __syncthreads();   // the ONLY barrier per plane

        // (4) h-window 3-tap, rotate z-ring, emit d = t-2
        a0 = a1; a1 = a2; b0 = b1; b1 = b2;
        {
            const int cc = (tx + 1) & 15;   // w-sum center lane; tx>=14 masked by valid
            a2 = sW[cb][ty][cc] + sW[cb][ty + 1][cc] + sW[cb][ty + 2][cc];
            b2 = sWB[cb][ty][cc] + sWB[cb][ty + 1][cc] + sWB[cb][ty + 2][cc];
        }

        const int d = t - 2;
        if (valid && d >= ds && d < de) {
            const h8 FA = a0 + a1 + a2;
            const h2 FB = b0 + b1 + b2;
            const float inv27 = 1.f / 27.f;
            const float dydx = (float)FA[0] * inv27, dxdx = (float)FA[1] * inv27, dzdx = (float)FA[2] * inv27;
            const float dydy = (float)FA[3] * inv27, dxdy = (float)FA[4] * inv27, dzdy = (float)FA[5] * inv27;
            const float dydz = (float)FA[6] * inv27, dxdz = (float)FA[7] * inv27, dzdz = (float)FB[0] * inv27;
            const float a = dxdx + 1.f, e = dydy + 1.f, iN = dzdz + 1.f;
            const float J = a * (e * iN - dydz * dzdy)
                          - dxdy * (dydx * iN - dydz * dzdx)
                          + dxdz * (dydx * dzdy - e * dzdx);
            const float Tr = a * a + dxdy * dxdy + dxdz * dxdz
                           + dydx * dydx + e * e + dydz * dydz
                           + dzdx * dzdx + dzdy * dzdy + iN * iN;
            const float stretch = Tr * __expf(1.f - J) - 3.f;
            const float vol = (J - 1.f) * (J - 1.f);
            // mu=1,lam=5 -> U = (1/12)*stretch + (15/31)*vol (verified exact)
            acc += 0.0833333358f * stretch + 0.4838709677f * vol;
        }

        // rotate rings: f16 center, raw f32 2-deep pipeline
        prev16_p = cur16_p; cur_p = nxt_p; nxt_p = n2_p;
        prev16_l = cur16_l; cur_l = nxt_l; nxt_l = n2_l;
    }

    // mean scaling (191^3)
    acc *= (1.f / 6967871.f);

    // wave reduce (64 lanes), then block reduce, one atomic per block
    #pragma unroll
    for (int off = 32; off > 0; off >>= 1) acc += __shfl_down(acc, off, 64);
    if ((tid & 63) == 0) wsum[tid >> 6] = acc;
    __syncthreads();
    if (tid == 0) {
        atomicAdd(out, wsum[0] + wsum[1] + wsum[2] + wsum[3]);
    }
}

extern "C" void kernel_launch(void* const* d_in, const int* in_sizes, int n_in,
                              void* d_out, int out_size, void* d_ws, size_t ws_size,
                              hipStream_t stream) {
    const float* y_pred = (const float*)d_in[0];
    float* out = (float*)d_out;

    // d_out is poisoned 0xAA before every timed launch — zero it (graph-capturable).
    hipMemsetAsync(out, 0, sizeof(float), stream);

    dim3 grid(NBW, NBH, NCH);
    nh_fused_kernel<<<grid, 256, 0, stream>>>(y_pred, out);
}

// Round 6
// 172.588 us; speedup vs baseline: 1.1329x; 1.1329x over previous
//
#include <hip/hip_runtime.h>
#include <math.h>

#define DIM 192
#define OD  191          // output domain per axis
#define PLANE 36864      // 192*192
#define VOL 7077888      // 192^3
#define TW  14           // tile width  (w)  -> 16-lane DPP row covers 16-wide halo
#define TH  16           // tile height (h)
#define CD  16           // d-planes per chunk
#define NBW 14           // ceil(191/14)
#define NBH 12           // ceil(191/16)
#define NCH 12           // 12*16 = 192 >= 191

typedef float    f4 __attribute__((ext_vector_type(4)));
typedef _Float16 h8 __attribute__((ext_vector_type(8)));
typedef _Float16 h4 __attribute__((ext_vector_type(4)));
typedef _Float16 h2 __attribute__((ext_vector_type(2)));

template<int CTRL>
__device__ __forceinline__ int dppi(int x) {
    // bound_ctrl=true: out-of-row / exec-off source reads as 0 (matches zero padding)
    return __builtin_amdgcn_update_dpp(0, x, CTRL, 0xF, 0xF, true);
}

union U8 { h8 v; int i[4]; };
union U2 { h2 v; int i; };

// Symmetric 3-tap w-window sum across a 16-lane DPP row:
//   out(lane) = in(lane-1) + in(lane) + in(lane+1), 0 outside the row.
__device__ __forceinline__ void wsum3(h8& a, h2& b) {
    U8 ua, s1, s2;
    ua.v = a;
    #pragma unroll
    for (int k = 0; k < 4; ++k) {
        s1.i[k] = dppi<0x101>(ua.i[k]);   // row_shl:1
        s2.i[k] = dppi<0x111>(ua.i[k]);   // row_shr:1
    }
    a = ua.v + s1.v + s2.v;
    U2 ub, t1, t2;
    ub.v = b;
    t1.i = dppi<0x101>(ub.i);
    t2.i = dppi<0x111>(ub.i);
    b = ub.v + t1.v + t2.v;
}

// Packed-f16 diff: c=center, cw=w+1, ch=h+1, cd=d+1 (all h4 {x,y,z,0}).
// Field order: va={hx,hy,hz,dx,dy,dz,wx,wy}, vb={wz,0}.
__device__ __forceinline__ void make_diff16(const h4 c, const h4 cw, const h4 ch, const h4 cd,
                                            h8& va, h2& vb) {
    const h4 dh = __builtin_elementwise_abs(ch - c);
    const h4 dd = __builtin_elementwise_abs(cd - c);
    const h4 dw = __builtin_elementwise_abs(cw - c);
    va = (h8){dh[0], dh[1], dh[2], dd[0], dd[1], dd[2], dw[0], dw[1]};
    vb = (h2){dw[2], (_Float16)0.f};
}

// Raw f32 load, NO dependent arithmetic in this iteration -> the vmcnt wait
// drifts into the NEXT iteration (keeps the software pipeline asynchronous).
__device__ __forceinline__ f4 ld3(const float* __restrict__ P, int idx, bool ok) {
    f4 r = (f4)0;
    if (ok) {
        r.x = P[idx];
        r.y = P[idx + VOL];
        r.z = P[idx + 2 * VOL];
    }
    return r;
}

// f32 -> packed f16 at STORE time: first use of the loaded value is one full
// iteration after the load was issued.
__device__ __forceinline__ h4 cvt16(const f4 v) {
    return (h4){(_Float16)v.x, (_Float16)v.y, (_Float16)v.z, (_Float16)0.f};
}

// Fused: diff -> separable 3x3x3 box mean (w: DPP, h: LDS 3-tap, z: register
// ring) -> neo-hookean energy -> mean reduction.
// Round-6: round-2 pipeline (1-DEEP raw-f32 prefetch, no same-iteration
// consumers of the load) + f16-packed LDS staging with cvt deferred to store
// time. Exactly one live prefetch plane -> no spills (r5's 2-deep spilled,
// WRITE_SIZE 63KB -> 8MB).
__global__ __launch_bounds__(256, 8)
void nh_fused_kernel(const float* __restrict__ P, float* __restrict__ out) {
    const int tid = threadIdx.x;
    const int tx  = tid & 15;        // lane within DPP row == w within halo
    const int ty  = tid >> 4;        // h within tile
    const int w0  = blockIdx.x * TW;
    const int h0  = blockIdx.y * TH;
    const int ds  = blockIdx.z * CD;
    const int de  = min(ds + CD, OD);

    __shared__ h4 sraw[2][19][18];   // raw y_pred (f16 packed), rows h0-1..h0+17, cols w0-1..w0+15
    __shared__ h8 sW[2][18][16];     // w-summed diffs, double-buffered by t parity
    __shared__ h2 sWB[2][18][16];    // w-summed {Wd2, 0}
    __shared__ float wsum[4];

    // ---- loop-invariant geometry ----
    // primary halo point (ty, tx): staged + built by every thread
    const int hp_p = h0 - 1 + ty;
    const int wp_p = w0 - 1 + tx;
    const bool in_raw_p  = (hp_p >= 0) & (hp_p < DIM) & (wp_p >= 0) & (wp_p < DIM);
    const bool in_diff_p = (hp_p >= 0) & (hp_p < OD)  & (wp_p >= 0) & (wp_p < OD);
    const int base_p = hp_p * DIM + wp_p;

    // leftover halo point: tids 0..47 -> rows 16..18 x cols 0..15 (so pass-2
    // threads 0..31 own exactly the rows-16/17 points they build);
    // tids 48..66 -> col 16, rows 0..18.
    int hh_l, ww_l;
    if (tid < 48) { hh_l = 16 + (tid >> 4); ww_l = tid & 15; }
    else          { hh_l = tid - 48;        ww_l = 16; }
    const bool has_l = (tid < 67);
    const int hp_l = h0 - 1 + hh_l;
    const int wp_l = w0 - 1 + ww_l;
    const bool in_raw_l  = has_l & (hp_l >= 0) & (hp_l < DIM) & (wp_l >= 0) & (wp_l < DIM);
    const bool in_diff_l = (tid < 32) & (hp_l >= 0) & (hp_l < OD) & (wp_l >= 0) & (wp_l < OD);
    const int base_l = hp_l * DIM + wp_l;

    const bool valid = (tx < TW) && (w0 + tx < OD) && (h0 + ty < OD);

    h8 a0 = (h8)0, a1 = (h8)0, a2 = (h8)0;
    h2 b0 = (h2)0, b1 = (h2)0, b2 = (h2)0;
    f4 cur_p = (f4)0, cur_l = (f4)0;        // raw f32 at plane t (loaded last iteration)
    h4 prev16_p = (h4)0, prev16_l = (h4)0;  // f16 of plane t-1 (diff center)
    float acc = 0.f;

    // preload plane t0 = ds-1 (zeros when t0 < 0)
    {
        const int t0 = ds - 1;
        if (t0 >= 0) {
            cur_p = ld3(P, t0 * PLANE + base_p, in_raw_p);
            cur_l = ld3(P, t0 * PLANE + base_l, in_raw_l);
        }
    }

    for (int t = ds - 1; t <= de + 1; ++t) {
        const int cb = t & 1, pb = cb ^ 1;

        // (1) prefetch plane t+1 into regs; consumed (first use = cvt) NEXT
        //     iteration, so the ~900cy HBM latency hides under this plane's work
        f4 nxt_p = (f4)0, nxt_l = (f4)0;
        {
            const int tn = t + 1;
            if ((tn < DIM) & (tn <= de + 1)) {       // wave-uniform
                nxt_p = ld3(P, tn * PLANE + base_p, in_raw_p);
                nxt_l = ld3(P, tn * PLANE + base_l, in_raw_l);
            }
        }

        // (2) convert plane t (loaded last iteration) to f16, stage to LDS
        const h4 cur16_p = cvt16(cur_p);
        sraw[cb][ty][tx] = cur16_p;
        h4 cur16_l = (h4)0;
        if (has_l) {
            cur16_l = cvt16(cur_l);
            sraw[cb][hh_l][ww_l] = cur16_l;
        }

        // (3) build w-summed diff plane p = t-1 into sW[cb]
        //     reads ONLY sraw[pb] (synced last iteration) + registers
        const bool built = (t >= ds) & (t - 1 >= 0) & (t - 1 < OD);   // wave-uniform

        {   // pass 1: rows 0..15 (all threads)
            h8 sa = (h8)0; h2 sb = (h2)0;
            if (built) {
                h8 va = (h8)0; h2 vb = (h2)0;
                if (in_diff_p) {
                    make_diff16(prev16_p,
                                sraw[pb][ty][tx + 1],     // (p, hp, wp+1)
                                sraw[pb][ty + 1][tx],     // (p, hp+1, wp)
                                cur16_p, va, vb);
                }
                wsum3(va, vb);                            // all lanes participate
                sa = va; sb = vb;
            }
            sW[cb][ty][tx] = sa; sWB[cb][ty][tx] = sb;
        }
        if (tid < 32) {  // pass 2: rows 16,17 in ONE wave issue (two DPP rows)
            h8 sa = (h8)0; h2 sb = (h2)0;
            if (built) {
                h8 va = (h8)0; h2 vb = (h2)0;
                if (in_diff_l) {
                    make_diff16(prev16_l,
                                sraw[pb][hh_l][ww_l + 1],
                                sraw[pb][hh_l + 1][ww_l],
                                cur16_l, va, vb);
                }
                wsum3(va, vb);
                sa = va; sb = vb;
            }
            sW[cb][hh_l][ww_l] = sa; sWB[cb][hh_l][ww_l] = sb;
        }

        __syncthreads();   // the ONLY barrier per plane

        // (4) h-window 3-tap, rotate z-ring, emit d = t-2
        a0 = a1; a1 = a2; b0 = b1; b1 = b2;
        {
            const int cc = (tx + 1) & 15;   // w-sum center lane; tx>=14 masked by valid
            a2 = sW[cb][ty][cc] + sW[cb][ty + 1][cc] + sW[cb][ty + 2][cc];
            b2 = sWB[cb][ty][cc] + sWB[cb][ty + 1][cc] + sWB[cb][ty + 2][cc];
        }

        const int d = t - 2;
        if (valid && d >= ds && d < de) {
            const h8 FA = a0 + a1 + a2;
            const h2 FB = b0 + b1 + b2;
            const float inv27 = 1.f / 27.f;
            const float dydx = (float)FA[0] * inv27, dxdx = (float)FA[1] * inv27, dzdx = (float)FA[2] * inv27;
            const float dydy = (float)FA[3] * inv27, dxdy = (float)FA[4] * inv27, dzdy = (float)FA[5] * inv27;
            const float dydz = (float)FA[6] * inv27, dxdz = (float)FA[7] * inv27, dzdz = (float)FB[0] * inv27;
            const float a = dxdx + 1.f, e = dydy + 1.f, iN = dzdz + 1.f;
            const float J = a * (e * iN - dydz * dzdy)
                          - dxdy * (dydx * iN - dydz * dzdx)
                          + dxdz * (dydx * dzdy - e * dzdx);
            const float Tr = a * a + dxdy * dxdy + dxdz * dxdz
                           + dydx * dydx + e * e + dydz * dydz
                           + dzdx * dzdx + dzdy * dzdy + iN * iN;
            const float stretch = Tr * __expf(1.f - J) - 3.f;
            const float vol = (J - 1.f) * (J - 1.f);
            // mu=1,lam=5 -> U = (1/12)*stretch + (15/31)*vol (verified exact)
            acc += 0.0833333358f * stretch + 0.4838709677f * vol;
        }

        // rotate rings
        prev16_p = cur16_p; cur_p = nxt_p;
        prev16_l = cur16_l; cur_l = nxt_l;
    }

    // mean scaling (191^3)
    acc *= (1.f / 6967871.f);

    // wave reduce (64 lanes), then block reduce, one atomic per block
    #pragma unroll
    for (int off = 32; off > 0; off >>= 1) acc += __shfl_down(acc, off, 64);
    if ((tid & 63) == 0) wsum[tid >> 6] = acc;
    __syncthreads();
    if (tid == 0) {
        atomicAdd(out, wsum[0] + wsum[1] + wsum[2] + wsum[3]);
    }
}

extern "C" void kernel_launch(void* const* d_in, const int* in_sizes, int n_in,
                              void* d_out, int out_size, void* d_ws, size_t ws_size,
                              hipStream_t stream) {
    const float* y_pred = (const float*)d_in[0];
    float* out = (float*)d_out;

    // d_out is poisoned 0xAA before every timed launch — zero it (graph-capturable).
    hipMemsetAsync(out, 0, sizeof(float), stream);

    dim3 grid(NBW, NBH, NCH);
    nh_fused_kernel<<<grid, 256, 0, stream>>>(y_pred, out);
}